// Round 3
// baseline (7528.072 us; speedup 1.0000x reference)
//
#include <hip/hip_runtime.h>
#include <math.h>

static constexpr int NN  = 20000;
static constexpr int TT  = 6;
static constexpr int EE  = 640000;
static constexpr int CINC = 3;
static constexpr int HH  = 64;

__global__ void deg_kernel(const int* __restrict__ dst, float* __restrict__ deg) {
    int e = blockIdx.x * blockDim.x + threadIdx.x;
    if (e < EE) atomicAdd(&deg[dst[e]], 1.0f);
}

__global__ void dinv_kernel(const float* __restrict__ deg, float* __restrict__ dinv) {
    int i = blockIdx.x * blockDim.x + threadIdx.x;
    if (i < NN) dinv[i] = rsqrtf(deg[i] + 1.0f);
}

// xw = x @ W1 ; agg = dinv^2 * xw  (self-loop init, avoids memset of agg)
__global__ void xw1_kernel(const float* __restrict__ x, const float* __restrict__ W1,
                           const float* __restrict__ dinv,
                           float* __restrict__ xw, float* __restrict__ agg) {
    int gid = blockIdx.x * blockDim.x + threadIdx.x;
    if (gid >= NN * HH) return;
    int node = gid >> 6, hh = gid & 63;
    const float* xr = x + node * CINC;
    float acc = 0.f;
#pragma unroll
    for (int k = 0; k < CINC; ++k) acc = fmaf(xr[k], W1[k * HH + hh], acc);
    xw[gid] = acc;
    float di = dinv[node];
    agg[gid] = di * di * acc;
}

// agg[dst] += xw[src] * dinv[src]*dinv[dst]  — 16 threads (float4) per edge
__global__ void scatter_kernel(const int* __restrict__ src, const int* __restrict__ dst,
                               const float* __restrict__ dinv, const float* __restrict__ xw,
                               float* __restrict__ agg) {
    int gid = blockIdx.x * blockDim.x + threadIdx.x;
    int e = gid >> 4;
    if (e >= EE) return;
    int q = gid & 15;
    int s = src[e], d = dst[e];
    float w = dinv[s] * dinv[d];
    const float4 v = *(const float4*)(xw + ((size_t)s << 6) + (q << 2));
    float* ad = agg + ((size_t)d << 6) + (q << 2);
    atomicAdd(ad + 0, v.x * w);
    atomicAdd(ad + 1, v.y * w);
    atomicAdd(ad + 2, v.z * w);
    atomicAdd(ad + 3, v.w * w);
}

__global__ void bias_relu_kernel(const float* __restrict__ agg, const float* __restrict__ b,
                                 float* __restrict__ z) {
    int gid = blockIdx.x * blockDim.x + threadIdx.x;
    if (gid >= NN * HH) return;
    float v = agg[gid] + b[gid & 63];
    z[gid] = v > 0.f ? v : 0.f;
}

// xw = z @ W2 ; agg = dinv^2 * xw
__global__ void xw2_kernel(const float* __restrict__ z, const float* __restrict__ W2,
                           const float* __restrict__ dinv,
                           float* __restrict__ xw, float* __restrict__ agg) {
    int gid = blockIdx.x * blockDim.x + threadIdx.x;
    if (gid >= NN * HH) return;
    int node = gid >> 6, hh = gid & 63;
    const float* zr = z + ((size_t)node << 6);
    float acc = 0.f;
#pragma unroll 8
    for (int k = 0; k < HH; ++k) acc = fmaf(zr[k], W2[k * HH + hh], acc);
    xw[gid] = acc;
    float di = dinv[node];
    agg[gid] = di * di * acc;
}

// w [rows][cols] -> wt [cols][rows]
__global__ void transpose_kernel(const float* __restrict__ w, float* __restrict__ wt,
                                 int rows, int cols) {
    int gid = blockIdx.x * blockDim.x + threadIdx.x;
    if (gid >= rows * cols) return;
    int r = gid / cols, c = gid - r * cols;
    wt[c * rows + r] = w[gid];
}

// torch GRUCell; weights pre-transposed so lane-j reads are coalesced
__global__ void gru_kernel(const float* __restrict__ z, const float* __restrict__ hin,
                           const float* __restrict__ wihT, const float* __restrict__ whhT,
                           const float* __restrict__ bih, const float* __restrict__ bhh,
                           float* __restrict__ hout) {
    int gid = blockIdx.x * blockDim.x + threadIdx.x;
    if (gid >= NN * HH) return;
    int node = gid >> 6, jj = gid & 63;
    const float* zr   = z   + ((size_t)node << 6);
    const float* hrow = hin + ((size_t)node << 6);
    float ir = 0, iz = 0, inn = 0, hr = 0, hz = 0, hn = 0;
    for (int k = 0; k < HH; ++k) {
        float zk = zr[k], hk = hrow[k];
        const float* wi = wihT + k * 192;
        const float* wh = whhT + k * 192;
        ir  = fmaf(zk, wi[jj],        ir);
        iz  = fmaf(zk, wi[64 + jj],   iz);
        inn = fmaf(zk, wi[128 + jj],  inn);
        hr  = fmaf(hk, wh[jj],        hr);
        hz  = fmaf(hk, wh[64 + jj],   hz);
        hn  = fmaf(hk, wh[128 + jj],  hn);
    }
    ir += bih[jj]; iz += bih[64 + jj]; inn += bih[128 + jj];
    hr += bhh[jj]; hz += bhh[64 + jj]; hn  += bhh[128 + jj];
    float r  = 1.f / (1.f + expf(-(ir + hr)));
    float zg = 1.f / (1.f + expf(-(iz + hz)));
    float ng = tanhf(inn + r * hn);
    hout[gid] = (1.f - zg) * ng + zg * hrow[jj];
}

__global__ void head1_kernel(const float* __restrict__ h, const float* __restrict__ W3,
                             const float* __restrict__ b3, float* __restrict__ hid) {
    int gid = blockIdx.x * blockDim.x + threadIdx.x;
    if (gid >= NN * HH) return;
    int node = gid >> 6, jj = gid & 63;
    const float* hrow = h + ((size_t)node << 6);
    float acc = b3[jj];
#pragma unroll 8
    for (int k = 0; k < HH; ++k) acc = fmaf(hrow[k], W3[k * HH + jj], acc);
    hid[gid] = acc > 0.f ? acc : 0.f;
}

// one wave per node: pred = sigmoid(hidden . W4 + b4)
__global__ void head2_kernel(const float* __restrict__ hid, const float* __restrict__ W4,
                             const float* __restrict__ b4, float* __restrict__ out) {
    int gid = blockIdx.x * blockDim.x + threadIdx.x;
    int node = gid >> 6;
    if (node >= NN) return;
    int lane = threadIdx.x & 63;
    float v = hid[((size_t)node << 6) + lane] * W4[lane];
    for (int off = 32; off; off >>= 1) v += __shfl_down(v, off);
    if (lane == 0) out[node] = 1.f / (1.f + expf(-(v + b4[0])));
}

extern "C" void kernel_launch(void* const* d_in, const int* in_sizes, int n_in,
                              void* d_out, int out_size, void* d_ws, size_t ws_size,
                              hipStream_t stream) {
    const float* nf    = (const float*)d_in[0];
    const int*   edges = (const int*)  d_in[1];
    const float* W1  = (const float*)d_in[2];
    const float* b1  = (const float*)d_in[3];
    const float* W2  = (const float*)d_in[4];
    const float* b2  = (const float*)d_in[5];
    const float* wih = (const float*)d_in[6];
    const float* whh = (const float*)d_in[7];
    const float* bih = (const float*)d_in[8];
    const float* bhh = (const float*)d_in[9];
    const float* W3  = (const float*)d_in[10];
    const float* b3  = (const float*)d_in[11];
    const float* W4  = (const float*)d_in[12];
    const float* b4  = (const float*)d_in[13];
    float* out = (float*)d_out;

    float* ws   = (float*)d_ws;
    float* deg  = ws;                         // NN
    float* dinv = deg + NN;                   // NN
    float* A    = dinv + NN;                  // NN*HH  (xw)
    float* B    = A + (size_t)NN * HH;        // NN*HH  (agg)
    float* C    = B + (size_t)NN * HH;        // NN*HH  (z / hidden)
    float* D    = C + (size_t)NN * HH;        // NN*HH  (h ping)
    float* Ebuf = D + (size_t)NN * HH;        // NN*HH  (h pong)
    float* wihT = Ebuf + (size_t)NN * HH;     // 64*192
    float* whhT = wihT + 192 * 64;            // 64*192

    const int BS = 256;
    const int gNH = (NN * HH + BS - 1) / BS;
    const int gE  = (EE + BS - 1) / BS;
    const int gS  = (EE * 16 + BS - 1) / BS;
    const int gN  = (NN + BS - 1) / BS;

    hipMemsetAsync(D, 0, (size_t)NN * HH * sizeof(float), stream);
    transpose_kernel<<<(192 * 64 + BS - 1) / BS, BS, 0, stream>>>(wih, wihT, 192, 64);
    transpose_kernel<<<(192 * 64 + BS - 1) / BS, BS, 0, stream>>>(whh, whhT, 192, 64);

    float* hin = D;
    float* hout = Ebuf;
    for (int t = 0; t < TT; ++t) {
        const int* src = edges + (size_t)t * 2 * EE;
        const int* dst = src + EE;
        const float* xt = nf + (size_t)t * NN * CINC;

        hipMemsetAsync(deg, 0, NN * sizeof(float), stream);
        deg_kernel<<<gE, BS, 0, stream>>>(dst, deg);
        dinv_kernel<<<gN, BS, 0, stream>>>(deg, dinv);

        xw1_kernel<<<gNH, BS, 0, stream>>>(xt, W1, dinv, A, B);
        scatter_kernel<<<gS, BS, 0, stream>>>(src, dst, dinv, A, B);
        bias_relu_kernel<<<gNH, BS, 0, stream>>>(B, b1, C);

        xw2_kernel<<<gNH, BS, 0, stream>>>(C, W2, dinv, A, B);
        scatter_kernel<<<gS, BS, 0, stream>>>(src, dst, dinv, A, B);
        bias_relu_kernel<<<gNH, BS, 0, stream>>>(B, b2, C);

        gru_kernel<<<gNH, BS, 0, stream>>>(C, hin, wihT, whhT, bih, bhh, hout);
        float* tmp = hin; hin = hout; hout = tmp;
    }

    head1_kernel<<<gNH, BS, 0, stream>>>(hin, W3, b3, C);
    head2_kernel<<<gNH, BS, 0, stream>>>(C, W4, b4, out);
}

// Round 4
// 1573.505 us; speedup vs baseline: 4.7843x; 4.7843x over previous
//
#include <hip/hip_runtime.h>
#include <math.h>

static constexpr int NN   = 20000;
static constexpr int TT   = 6;
static constexpr int EE   = 640000;
static constexpr int CINC = 3;
static constexpr int HH   = 64;

// ---- CSR build ----------------------------------------------------------
__global__ void count_kernel(const int* __restrict__ dst, int* __restrict__ cnt) {
    int e = blockIdx.x * blockDim.x + threadIdx.x;
    if (e < EE) atomicAdd(&cnt[dst[e]], 1);
}

__global__ void dinv_kernel(const int* __restrict__ cnt, float* __restrict__ dinv) {
    int i = blockIdx.x * blockDim.x + threadIdx.x;
    if (i < NN) dinv[i] = rsqrtf((float)cnt[i] + 1.0f);
}

// single block, 1024 threads: exclusive scan of cnt[0..NN) -> rowptr, cursor
__global__ void scan_kernel(const int* __restrict__ cnt, int* __restrict__ rowptr,
                            int* __restrict__ cursor) {
    __shared__ int part[1024];
    const int CHUNK = 20;  // 1024*20 = 20480 >= NN
    int tid = threadIdx.x;
    int base = tid * CHUNK;
    int local[CHUNK];
    int s = 0;
#pragma unroll
    for (int i = 0; i < CHUNK; ++i) {
        int idx = base + i;
        int v = (idx < NN) ? cnt[idx] : 0;
        local[i] = s;
        s += v;
    }
    part[tid] = s;
    __syncthreads();
    for (int off = 1; off < 1024; off <<= 1) {
        int v = part[tid];
        int add = (tid >= off) ? part[tid - off] : 0;
        __syncthreads();
        part[tid] = v + add;
        __syncthreads();
    }
    int ebase = (tid == 0) ? 0 : part[tid - 1];
#pragma unroll
    for (int i = 0; i < CHUNK; ++i) {
        int idx = base + i;
        if (idx < NN) {
            int v = ebase + local[i];
            rowptr[idx] = v;
            cursor[idx] = v;
        }
    }
    if (tid == 1023) rowptr[NN] = part[1023];
}

__global__ void fill_kernel(const int* __restrict__ src, const int* __restrict__ dst,
                            int* __restrict__ cursor, int* __restrict__ col) {
    int e = blockIdx.x * blockDim.x + threadIdx.x;
    if (e >= EE) return;
    int d = dst[e];
    int pos = atomicAdd(&cursor[d], 1);
    col[pos] = src[e];
}

// ---- GCN dense parts ----------------------------------------------------
// y = dinv * (x @ W1)   (x is [N,3])
__global__ void y1_kernel(const float* __restrict__ x, const float* __restrict__ W1,
                          const float* __restrict__ dinv, float* __restrict__ y) {
    int gid = blockIdx.x * blockDim.x + threadIdx.x;
    if (gid >= NN * HH) return;
    int node = gid >> 6, hh = gid & 63;
    const float* xr = x + node * CINC;
    float acc = 0.f;
#pragma unroll
    for (int k = 0; k < CINC; ++k) acc = fmaf(xr[k], W1[k * HH + hh], acc);
    y[gid] = dinv[node] * acc;
}

// y = dinv * (z @ W2)   (z is [N,64])
__global__ void y2_kernel(const float* __restrict__ z, const float* __restrict__ W2,
                          const float* __restrict__ dinv, float* __restrict__ y) {
    int gid = blockIdx.x * blockDim.x + threadIdx.x;
    if (gid >= NN * HH) return;
    int node = gid >> 6, hh = gid & 63;
    const float* zr = z + ((size_t)node << 6);
    float acc = 0.f;
#pragma unroll 8
    for (int k = 0; k < HH; ++k) acc = fmaf(zr[k], W2[k * HH + hh], acc);
    y[gid] = dinv[node] * acc;
}

// ---- CSR gather: z[n] = relu(dinv[n]*(sum_{s in N(n)} y[s] + y[n]) + b)
// one 64-lane wave per node, lane = feature index
__global__ void gather_kernel(const int* __restrict__ rowptr, const int* __restrict__ col,
                              const float* __restrict__ dinv, const float* __restrict__ y,
                              const float* __restrict__ b, float* __restrict__ z) {
    int gid = blockIdx.x * blockDim.x + threadIdx.x;
    int node = gid >> 6;
    if (node >= NN) return;
    int lane = threadIdx.x & 63;
    int p = rowptr[node], pe = rowptr[node + 1];
    float acc = y[((size_t)node << 6) + lane];  // self term
    for (; p + 3 < pe; p += 4) {
        int c0 = col[p], c1 = col[p + 1], c2 = col[p + 2], c3 = col[p + 3];
        float v0 = y[((size_t)c0 << 6) + lane];
        float v1 = y[((size_t)c1 << 6) + lane];
        float v2 = y[((size_t)c2 << 6) + lane];
        float v3 = y[((size_t)c3 << 6) + lane];
        acc += (v0 + v1) + (v2 + v3);
    }
    for (; p < pe; ++p) acc += y[((size_t)col[p] << 6) + lane];
    float v = dinv[node] * acc + b[lane];
    z[((size_t)node << 6) + lane] = v > 0.f ? v : 0.f;
}

// ---- weight transpose (w [rows][cols] -> wt [cols][rows]) ---------------
__global__ void transpose_kernel(const float* __restrict__ w, float* __restrict__ wt,
                                 int rows, int cols) {
    int gid = blockIdx.x * blockDim.x + threadIdx.x;
    if (gid >= rows * cols) return;
    int r = gid / cols, c = gid - r * cols;
    wt[c * rows + r] = w[gid];
}

// ---- GRU cell (torch semantics) -----------------------------------------
__global__ void gru_kernel(const float* __restrict__ z, const float* __restrict__ hin,
                           const float* __restrict__ wihT, const float* __restrict__ whhT,
                           const float* __restrict__ bih, const float* __restrict__ bhh,
                           float* __restrict__ hout) {
    int gid = blockIdx.x * blockDim.x + threadIdx.x;
    if (gid >= NN * HH) return;
    int node = gid >> 6, jj = gid & 63;
    const float* zr   = z   + ((size_t)node << 6);
    const float* hrow = hin + ((size_t)node << 6);
    float ir = 0, iz = 0, inn = 0, hr = 0, hz = 0, hn = 0;
    for (int k = 0; k < HH; ++k) {
        float zk = zr[k], hk = hrow[k];
        const float* wi = wihT + k * 192;
        const float* wh = whhT + k * 192;
        ir  = fmaf(zk, wi[jj],        ir);
        iz  = fmaf(zk, wi[64 + jj],   iz);
        inn = fmaf(zk, wi[128 + jj],  inn);
        hr  = fmaf(hk, wh[jj],        hr);
        hz  = fmaf(hk, wh[64 + jj],   hz);
        hn  = fmaf(hk, wh[128 + jj],  hn);
    }
    ir += bih[jj]; iz += bih[64 + jj]; inn += bih[128 + jj];
    hr += bhh[jj]; hz += bhh[64 + jj]; hn  += bhh[128 + jj];
    float r  = 1.f / (1.f + expf(-(ir + hr)));
    float zg = 1.f / (1.f + expf(-(iz + hz)));
    float ng = tanhf(inn + r * hn);
    hout[gid] = (1.f - zg) * ng + zg * hrow[jj];
}

// ---- MLP head -----------------------------------------------------------
__global__ void head1_kernel(const float* __restrict__ h, const float* __restrict__ W3,
                             const float* __restrict__ b3, float* __restrict__ hid) {
    int gid = blockIdx.x * blockDim.x + threadIdx.x;
    if (gid >= NN * HH) return;
    int node = gid >> 6, jj = gid & 63;
    const float* hrow = h + ((size_t)node << 6);
    float acc = b3[jj];
#pragma unroll 8
    for (int k = 0; k < HH; ++k) acc = fmaf(hrow[k], W3[k * HH + jj], acc);
    hid[gid] = acc > 0.f ? acc : 0.f;
}

__global__ void head2_kernel(const float* __restrict__ hid, const float* __restrict__ W4,
                             const float* __restrict__ b4, float* __restrict__ out) {
    int gid = blockIdx.x * blockDim.x + threadIdx.x;
    int node = gid >> 6;
    if (node >= NN) return;
    int lane = threadIdx.x & 63;
    float v = hid[((size_t)node << 6) + lane] * W4[lane];
    for (int off = 32; off; off >>= 1) v += __shfl_down(v, off);
    if (lane == 0) out[node] = 1.f / (1.f + expf(-(v + b4[0])));
}

extern "C" void kernel_launch(void* const* d_in, const int* in_sizes, int n_in,
                              void* d_out, int out_size, void* d_ws, size_t ws_size,
                              hipStream_t stream) {
    const float* nf    = (const float*)d_in[0];
    const int*   edges = (const int*)  d_in[1];
    const float* W1  = (const float*)d_in[2];
    const float* b1  = (const float*)d_in[3];
    const float* W2  = (const float*)d_in[4];
    const float* b2  = (const float*)d_in[5];
    const float* wih = (const float*)d_in[6];
    const float* whh = (const float*)d_in[7];
    const float* bih = (const float*)d_in[8];
    const float* bhh = (const float*)d_in[9];
    const float* W3  = (const float*)d_in[10];
    const float* b3  = (const float*)d_in[11];
    const float* W4  = (const float*)d_in[12];
    const float* b4  = (const float*)d_in[13];
    float* out = (float*)d_out;

    // workspace layout: ints first, then floats
    int* wsi    = (int*)d_ws;
    int* cnt    = wsi;                 // NN
    int* rowptr = cnt + NN;            // NN+1
    int* cursor = rowptr + NN + 1;     // NN
    int* col    = cursor + NN;         // EE
    float* wsf  = (float*)(col + EE);
    float* dinv = wsf;                       // NN
    float* Y    = dinv + NN;                 // NN*HH (y)
    float* Z    = Y + (size_t)NN * HH;       // NN*HH (z / hidden)
    float* Hp   = Z + (size_t)NN * HH;       // NN*HH (h ping)
    float* Hq   = Hp + (size_t)NN * HH;      // NN*HH (h pong)
    float* wihT = Hq + (size_t)NN * HH;      // 192*64
    float* whhT = wihT + 192 * 64;           // 192*64

    const int BS  = 256;
    const int gNH = (NN * HH + BS - 1) / BS;
    const int gE  = (EE + BS - 1) / BS;
    const int gN  = (NN + BS - 1) / BS;

    hipMemsetAsync(Hp, 0, (size_t)NN * HH * sizeof(float), stream);
    transpose_kernel<<<(192 * 64 + BS - 1) / BS, BS, 0, stream>>>(wih, wihT, 192, 64);
    transpose_kernel<<<(192 * 64 + BS - 1) / BS, BS, 0, stream>>>(whh, whhT, 192, 64);

    float* hin = Hp;
    float* hout = Hq;
    for (int t = 0; t < TT; ++t) {
        const int* src = edges + (size_t)t * 2 * EE;
        const int* dst = src + EE;
        const float* xt = nf + (size_t)t * NN * CINC;

        // CSR build (shared by both GCN layers)
        hipMemsetAsync(cnt, 0, NN * sizeof(int), stream);
        count_kernel<<<gE, BS, 0, stream>>>(dst, cnt);
        dinv_kernel<<<gN, BS, 0, stream>>>(cnt, dinv);
        scan_kernel<<<1, 1024, 0, stream>>>(cnt, rowptr, cursor);
        fill_kernel<<<gE, BS, 0, stream>>>(src, dst, cursor, col);

        // GCN layer 1
        y1_kernel<<<gNH, BS, 0, stream>>>(xt, W1, dinv, Y);
        gather_kernel<<<gNH, BS, 0, stream>>>(rowptr, col, dinv, Y, b1, Z);

        // GCN layer 2
        y2_kernel<<<gNH, BS, 0, stream>>>(Z, W2, dinv, Y);
        gather_kernel<<<gNH, BS, 0, stream>>>(rowptr, col, dinv, Y, b2, Z);

        // GRU
        gru_kernel<<<gNH, BS, 0, stream>>>(Z, hin, wihT, whhT, bih, bhh, hout);
        float* tmp = hin; hin = hout; hout = tmp;
    }

    head1_kernel<<<gNH, BS, 0, stream>>>(hin, W3, b3, Z);
    head2_kernel<<<gNH, BS, 0, stream>>>(Z, W4, b4, out);
}